// Round 1
// baseline (246.734 us; speedup 1.0000x reference)
//
#include <hip/hip_runtime.h>
#include <hip/hip_bf16.h>

// Problem constants (fixed by reference)
#define BATCH 2
#define NPTS  8192
#define BN    (BATCH * NPTS)   // 16384
#define KNN   16
#define HEADS 4
#define DHEAD 32
#define HD    128              // HEADS*DHEAD
#define CIN   64
#define COUT  128
#define WCOLS 384              // [WqA1 | WkA1 | Wv]

// ---------------------------------------------------------------------------
// Kernel P: fold weights.
//   Wcat[64][384]: cols 0..127  = Wq@A1, 128..255 = Wk@A1, 256..383 = Wv
//   P2A1[3][128]  = P2@A1
//   cvec[128]     = b1 + bp2@A1     (constant part of pre-ReLU z)
// ---------------------------------------------------------------------------
__global__ void prep_kernel(const float* __restrict__ Wk,
                            const float* __restrict__ Wv,
                            const float* __restrict__ Wq,
                            const float* __restrict__ A1,
                            const float* __restrict__ b1,
                            const float* __restrict__ P2,
                            const float* __restrict__ bp2,
                            float* __restrict__ Wcat,
                            float* __restrict__ P2A1,
                            float* __restrict__ cvec) {
    int t = blockIdx.x * blockDim.x + threadIdx.x;
    if (t < CIN * WCOLS) {
        int i = t / WCOLS, j = t % WCOLS;
        float acc = 0.f;
        if (j < HD) {
            for (int m = 0; m < HD; ++m) acc += Wq[i*HD + m] * A1[m*HD + j];
        } else if (j < 2*HD) {
            int jj = j - HD;
            for (int m = 0; m < HD; ++m) acc += Wk[i*HD + m] * A1[m*HD + jj];
        } else {
            acc = Wv[i*HD + (j - 2*HD)];
        }
        Wcat[t] = acc;
    } else if (t < CIN*WCOLS + 3*HD) {
        int u = t - CIN*WCOLS;
        int r = u / HD, j = u % HD;
        float acc = 0.f;
        for (int m = 0; m < HD; ++m) acc += P2[r*HD + m] * A1[m*HD + j];
        P2A1[u] = acc;
    } else if (t < CIN*WCOLS + 3*HD + HD) {
        int j = t - (CIN*WCOLS + 3*HD);
        float acc = b1[j];
        for (int m = 0; m < HD; ++m) acc += bp2[m] * A1[m*HD + j];
        cvec[j] = acc;
    }
}

// ---------------------------------------------------------------------------
// Kernel A: QKV[p][0:128]   = F[p] @ (Wq@A1) + cvec   (pre-ReLU z, query part)
//           QKV[p][128:256] = F[p] @ (Wk@A1)
//           QKV[p][256:384] = F[p] @ Wv
// 8 points per block so Wcat gets 8x reuse out of L2.
// ---------------------------------------------------------------------------
#define PPB 8
__global__ __launch_bounds__(128) void qkv_kernel(const float* __restrict__ F,
                                                  const float* __restrict__ Wcat,
                                                  const float* __restrict__ cvec,
                                                  float* __restrict__ QKV) {
    int p0 = blockIdx.x * PPB;
    int t = threadIdx.x;   // 0..127
    __shared__ float fs[PPB][CIN];
    for (int u = t; u < PPB * CIN; u += 128)
        fs[u / CIN][u % CIN] = F[(p0 + u / CIN) * CIN + (u % CIN)];
    __syncthreads();
    for (int r = 0; r < 3; ++r) {
        int j = r * 128 + t;
        float base = (j < HD) ? cvec[j] : 0.f;
        float acc[PPB];
        #pragma unroll
        for (int p = 0; p < PPB; ++p) acc[p] = base;
        for (int i = 0; i < CIN; ++i) {
            float w = Wcat[i * WCOLS + j];
            #pragma unroll
            for (int p = 0; p < PPB; ++p) acc[p] += fs[p][i] * w;
        }
        #pragma unroll
        for (int p = 0; p < PPB; ++p)
            QKV[(p0 + p) * WCOLS + j] = acc[p];
    }
}

// ---------------------------------------------------------------------------
// Kernel B: per-point attention. One block (128 threads) per point;
// thread = channel c.
//   z_k[c]  = qz[c] - kA1[idx_k][c] + h@P2A1[:,c]          (then ReLU)
//   pe_k[c] = h@P2[:,c] + bp2[c]
//   logit[k][h] = relu(z_k) . A2[:,h] + b2[h]; softmax over k per head
//   fused[c] = sum_k attn[k][c/32] * (V[idx_k][c] + pe_k[c])
//   out[c]   = fused @ Wout[:,c] + bout[c]
// ---------------------------------------------------------------------------
__global__ __launch_bounds__(128) void attn_kernel(
        const float* __restrict__ xyzs, const int* __restrict__ kg,
        const float* __restrict__ QKV,
        const float* __restrict__ P1, const float* __restrict__ bp1,
        const float* __restrict__ P2, const float* __restrict__ bp2,
        const float* __restrict__ P2A1,
        const float* __restrict__ A2, const float* __restrict__ b2,
        const float* __restrict__ Wout, const float* __restrict__ bout,
        float* __restrict__ out) {
    int p = blockIdx.x;           // 0..BN-1
    int b = p / NPTS;
    int t = threadIdx.x;          // 0..127 = channel

    __shared__ float zr[KNN][HD + 1];   // +1 pad: logits phase reads column-wise
    __shared__ float vs[KNN][HD + 1];
    __shared__ float lg[KNN][HEADS];
    __shared__ float at[KNN][HEADS];
    __shared__ float fused[HD];

    // Hoist uniform small weights into registers.
    float p1r[9], bp1r[3];
    #pragma unroll
    for (int i = 0; i < 9; ++i) p1r[i] = P1[i];
    #pragma unroll
    for (int i = 0; i < 3; ++i) bp1r[i] = bp1[i];

    float qz = QKV[p * WCOLS + t];
    float pa0 = P2A1[t], pa1 = P2A1[HD + t], pa2 = P2A1[2*HD + t];
    float p20 = P2[t],   p21 = P2[HD + t],  p22 = P2[2*HD + t];
    float bp2t = bp2[t];
    float x0 = xyzs[p*3 + 0], x1 = xyzs[p*3 + 1], x2 = xyzs[p*3 + 2];

    #pragma unroll
    for (int k = 0; k < KNN; ++k) {
        int idx = kg[p * KNN + k];
        int q = b * NPTS + idx;
        float r0 = x0 - xyzs[q*3 + 0];
        float r1 = x1 - xyzs[q*3 + 1];
        float r2 = x2 - xyzs[q*3 + 2];
        float h0 = fmaxf(r0*p1r[0] + r1*p1r[3] + r2*p1r[6] + bp1r[0], 0.f);
        float h1 = fmaxf(r0*p1r[1] + r1*p1r[4] + r2*p1r[7] + bp1r[1], 0.f);
        float h2 = fmaxf(r0*p1r[2] + r1*p1r[5] + r2*p1r[8] + bp1r[2], 0.f);
        float krow = QKV[q * WCOLS + HD + t];
        float vrow = QKV[q * WCOLS + 2*HD + t];
        float z = qz - krow + h0*pa0 + h1*pa1 + h2*pa2;
        zr[k][t] = fmaxf(z, 0.f);
        float pe = h0*p20 + h1*p21 + h2*p22 + bp2t;
        vs[k][t] = vrow + pe;
    }
    __syncthreads();

    // logits: 64 threads, one (k,h) each, 128-length dot from LDS
    if (t < KNN * HEADS) {
        int k = t >> 2, h = t & 3;
        float acc = b2[h];
        #pragma unroll 4
        for (int c = 0; c < HD; ++c) acc += zr[k][c] * A2[c * HEADS + h];
        lg[k][h] = acc;
    }
    __syncthreads();

    // softmax over K per head
    if (t < HEADS) {
        float m = -1e30f;
        #pragma unroll
        for (int k = 0; k < KNN; ++k) m = fmaxf(m, lg[k][t]);
        float e[KNN], s = 0.f;
        #pragma unroll
        for (int k = 0; k < KNN; ++k) { e[k] = __expf(lg[k][t] - m); s += e[k]; }
        float inv = 1.f / s;
        #pragma unroll
        for (int k = 0; k < KNN; ++k) at[k][t] = e[k] * inv;
    }
    __syncthreads();

    // weighted reduce over neighbors
    int h = t >> 5;   // channel -> head (D=32)
    float f = 0.f;
    #pragma unroll
    for (int k = 0; k < KNN; ++k) f += at[k][h] * vs[k][t];
    fused[t] = f;
    __syncthreads();

    // output projection
    float acc = bout[t];
    #pragma unroll 4
    for (int j = 0; j < HD; ++j) acc += fused[j] * Wout[j * COUT + t];
    out[p * COUT + t] = acc;
}

// ---------------------------------------------------------------------------
extern "C" void kernel_launch(void* const* d_in, const int* in_sizes, int n_in,
                              void* d_out, int out_size, void* d_ws, size_t ws_size,
                              hipStream_t stream) {
    const float* xyzs = (const float*)d_in[0];
    const float* feat = (const float*)d_in[1];
    const int*   kg   = (const int*)  d_in[2];
    const float* Wk   = (const float*)d_in[3];
    const float* Wv   = (const float*)d_in[4];
    const float* Wq   = (const float*)d_in[5];
    const float* A1   = (const float*)d_in[6];
    const float* b1   = (const float*)d_in[7];
    const float* A2   = (const float*)d_in[8];
    const float* b2   = (const float*)d_in[9];
    const float* P1   = (const float*)d_in[10];
    const float* bp1  = (const float*)d_in[11];
    const float* P2   = (const float*)d_in[12];
    const float* bp2  = (const float*)d_in[13];
    const float* Wout = (const float*)d_in[14];
    const float* bout = (const float*)d_in[15];
    float* out = (float*)d_out;

    float* ws   = (float*)d_ws;
    float* Wcat = ws;                      // 64*384      = 24576 floats
    float* P2A1 = ws + 24576;              // 3*128       = 384
    float* cvec = ws + 24960;              // 128
    float* QKV  = ws + 25088;              // 16384*384   = 6291456 floats (~24 MB)

    int prep_elems = CIN*WCOLS + 3*HD + HD;        // 25088
    prep_kernel<<<(prep_elems + 255) / 256, 256, 0, stream>>>(
        Wk, Wv, Wq, A1, b1, P2, bp2, Wcat, P2A1, cvec);

    qkv_kernel<<<BN / PPB, 128, 0, stream>>>(feat, Wcat, cvec, QKV);

    attn_kernel<<<BN, 128, 0, stream>>>(
        xyzs, kg, QKV, P1, bp1, P2, bp2, P2A1, A2, b2, Wout, bout, out);
}